// Round 8
// baseline (254.849 us; speedup 1.0000x reference)
//
#include <hip/hip_runtime.h>
#include <hip/hip_bf16.h>
#include <math.h>

#define BB 2
#define SS 2048
#define DMM 1024
#define HH 16
#define HDD 64
#define NGLOB 32
#define MM 4096   // B*S
#define SCALE2 0.18033688f   // 0.125 * log2(e): exp(s/8) == exp2(s*SCALE2)

typedef __attribute__((ext_vector_type(8))) short short8;
typedef __attribute__((ext_vector_type(4))) float float4v;

__device__ __forceinline__ short f2bf(float f) {
    union { float f; unsigned u; } x; x.f = f;
    unsigned r = (x.u + 0x7fffu + ((x.u >> 16) & 1u)) >> 16;  // RNE
    return (short)r;
}

// async 16B global->LDS (m97 path). LDS dest = wave-uniform base + lane*16.
#define ASYNC16(gp, lp) __builtin_amdgcn_global_load_lds( \
    (__attribute__((address_space(1))) void*)(gp), \
    (__attribute__((address_space(3))) void*)(lp), 16, 0, 0)

// Vt slot swizzle: key-chunk XORed with dim-derived tag -> breaks the
// dim*stride==0 (mod 32 banks) collapse on transpose stores (16-way -> 4-way).
#define VSL(dim, key) ((dim) * 40 + (((((key) >> 3) ^ (((dim) >> 3) & 3)) << 3) | ((key) & 7)))

// ---------------- flat convert fp32->bf16 + setup_globals (block 8192) ----------------
// Exact 1D grid (8193 blocks): q 0..2047, k 2048..4095, v 4096..6143, weights 6144..8191
// (512 each), setup 8192. No idle blocks.
__global__ __launch_bounds__(256)
void convert_flat(const float* __restrict__ q, const float* __restrict__ k,
                  const float* __restrict__ v,
                  const float* __restrict__ w0, const float* __restrict__ w1,
                  const float* __restrict__ w2, const float* __restrict__ w3,
                  short* __restrict__ abf, short* __restrict__ wbf,
                  const int* __restrict__ gidx, int* __restrict__ g,
                  int* __restrict__ glist, int* __restrict__ gcount,
                  int* __restrict__ bcnt) {
    int bid = blockIdx.x;
    int t = threadIdx.x;
    if (bid == 6144 + 2048) {          // setup_globals + zero merge counters
        for (int i = t; i < SS; i += 256) g[i] = 0;
        if (t == 0) *gcount = 0;
        if (t < 32) bcnt[t] = 0;
        __syncthreads();
        if (t < NGLOB) {
            int j = gidx[t];
            if (j >= 0 && j < SS) g[j] = 1;
        }
        __syncthreads();
        for (int j = t; j < SS; j += 256) {
            if (g[j]) {
                int p = atomicAdd(gcount, 1);
                glist[p] = j;
            }
        }
        return;
    }
    const float* src;
    short* dst;
    if (bid < 6144) {                  // q/k/v: 4M elems each = 2048 blocks each
        int z = bid >> 11;
        size_t off = ((size_t)(bid & 2047) << 11) + (size_t)t * 8;
        src = ((z == 0) ? q : (z == 1) ? k : v) + off;
        dst = abf + ((size_t)z << 22) + off;
    } else {                           // weights: 1M elems each = 512 blocks each
        int y = (bid - 6144) >> 9;
        size_t off = ((size_t)((bid - 6144) & 511) << 11) + (size_t)t * 8;
        src = ((y == 0) ? w0 : (y == 1) ? w1 : (y == 2) ? w2 : w3) + off;
        dst = wbf + ((size_t)y << 20) + off;
    }
    float4 a = *(const float4*)(src);
    float4 b = *(const float4*)(src + 4);
    short8 s;
    s[0]=f2bf(a.x); s[1]=f2bf(a.y); s[2]=f2bf(a.z); s[3]=f2bf(a.w);
    s[4]=f2bf(b.x); s[5]=f2bf(b.y); s[6]=f2bf(b.z); s[7]=f2bf(b.w);
    *(short8*)dst = s;
}

// ---------------- 256x256/BK=64 MFMA GEMM: true 8-phase interleave (R6-verified) ----------------
// UNCHANGED from R6 (protect the win).
template<int OBF, int HEADSPLIT>
__global__ __launch_bounds__(512, 2)
void gemm256(const short* __restrict__ Abase, const short* __restrict__ Wbase,
             const float* __restrict__ b0, const float* __restrict__ b1,
             const float* __restrict__ b2,
             void* __restrict__ O0p, void* __restrict__ O1p, void* __restrict__ O2p) {
    __shared__ short As[2][256 * 64];   // 64 KB
    __shared__ short Ws[2][256 * 64];   // 64 KB

    int t = threadIdx.x;
    int z = blockIdx.y;
    const short* A    = Abase + (size_t)z * ((size_t)MM * DMM);
    const short* W    = Wbase + (size_t)z * ((size_t)DMM * DMM);
    const float* bias = (z == 0) ? b0 : (z == 1) ? b1 : b2;
    void* outp        = (z == 0) ? O0p : (z == 1) ? O1p : O2p;

    int bid = blockIdx.x;
    int mt = bid & 15, nt = bid >> 4;   // bid%8 == mt%8: nt-blocks of one mt share an XCD
    int m0 = mt * 256, n0 = nt * 256;

    int lane = t & 63, w = t >> 6;
    int quad = lane >> 4, col = lane & 15;
    int wm = (w >> 2) * 128;
    int wn = (w & 3) * 64;

    float4v acc[8][4];
    #pragma unroll
    for (int i = 0; i < 8; i++)
        #pragma unroll
        for (int j = 0; j < 4; j++) acc[i][j] = (float4v){0, 0, 0, 0};

    int srow = t >> 3;
    int scol = ((t & 7) ^ (srow & 7)) * 8;
    const short* Ap = A + (size_t)(m0 + srow) * DMM + scol;
    const short* Wp = W + (size_t)(n0 + srow) * DMM + scol;

    #define ST_W(bf, tt, h) ASYNC16(Wp + (size_t)(h) * 64 * DMM + (size_t)(tt) * 64, \
                                    &Ws[bf][(h) * 4096 + t * 8])
    #define ST_A(bf, tt, h) ASYNC16(Ap + (size_t)(h) * 64 * DMM + (size_t)(tt) * 64, \
                                    &As[bf][(h) * 4096 + t * 8])

    int c7 = col & 7;

    // prologue: stage step 0 in counted order, certify idx 0..5
    ST_W(0, 0, 0); ST_W(0, 0, 1); ST_W(0, 0, 2); ST_W(0, 0, 3);
    ST_A(0, 0, 0); ST_A(0, 0, 2); ST_A(0, 0, 1); ST_A(0, 0, 3);
    asm volatile("s_waitcnt vmcnt(2)" ::: "memory");
    __builtin_amdgcn_s_barrier();

    for (int it = 0; it < 16; it++) {
        int cur = it & 1, nb = cur ^ 1;
        bool pf = (it < 15);

        short8 bF[4][2];
        #pragma unroll
        for (int j = 0; j < 4; j++) {
            int rB = (wn + 16 * j + col) * 64;
            #pragma unroll
            for (int ks = 0; ks < 2; ks++)
                bF[j][ks] = *(short8*)&Ws[cur][rB + ((((ks << 2) | quad) ^ c7) << 3)];
        }

        #pragma unroll
        for (int p = 0; p < 4; p++) {
            short8 aF[2][2];
            #pragma unroll
            for (int u = 0; u < 2; u++) {
                int rA = (wm + 16 * (2 * p + u) + col) * 64;
                #pragma unroll
                for (int ks = 0; ks < 2; ks++)
                    aF[u][ks] = *(short8*)&As[cur][rA + ((((ks << 2) | quad) ^ c7) << 3)];
            }
            if (pf) {
                if (p == 0)      { ST_W(nb, it + 1, 0); ST_W(nb, it + 1, 1); }
                else if (p == 1) { ST_W(nb, it + 1, 2); ST_W(nb, it + 1, 3); }
                else if (p == 2) { ST_A(nb, it + 1, 0); ST_A(nb, it + 1, 2); }
                else             { ST_A(nb, it + 1, 1); ST_A(nb, it + 1, 3); }
            }
            __builtin_amdgcn_s_barrier();
            __builtin_amdgcn_s_setprio(1);
            #pragma unroll
            for (int ks = 0; ks < 2; ks++)
                #pragma unroll
                for (int u = 0; u < 2; u++)
                    #pragma unroll
                    for (int j = 0; j < 4; j++)
                        acc[2 * p + u][j] = __builtin_amdgcn_mfma_f32_16x16x32_bf16(
                            aF[u][ks], bF[j][ks], acc[2 * p + u][j], 0, 0, 0);
            __builtin_amdgcn_s_setprio(0);
            if (p == 1) {
                if (pf) asm volatile("s_waitcnt vmcnt(4)" ::: "memory");
                else    asm volatile("s_waitcnt vmcnt(0)" ::: "memory");
            }
            if (p == 3 && pf)
                asm volatile("s_waitcnt vmcnt(2)" ::: "memory");
            __builtin_amdgcn_s_barrier();
        }
    }
    #undef ST_W
    #undef ST_A

    #pragma unroll
    for (int i = 0; i < 8; i++) {
        #pragma unroll
        for (int j = 0; j < 4; j++) {
            int n = n0 + wn + 16 * j + col;
            float bn = bias[n];
            #pragma unroll
            for (int r = 0; r < 4; r++) {
                int m = m0 + wm + 16 * i + quad * 4 + r;
                float val = acc[i][j][r] + bn;
                size_t idx;
                if (HEADSPLIT) {
                    int b = m >> 11;
                    int s = m & 2047;
                    int h = n >> 6;
                    int hd = n & 63;
                    idx = (((size_t)b * HH + h) * SS + s) * HDD + hd;
                } else {
                    idx = (size_t)m * DMM + n;
                }
                if (OBF) ((short*)outp)[idx] = f2bf(val);
                else     ((float*)outp)[idx] = val;
            }
        }
    }
}

// ---------------- Wo GEMM: 128x128/BK=64, 512 thr, T2 swizzle + counted vmcnt + T5 --------------
// UNCHANGED from R5/R6. 256 blocks = full CU coverage.
__global__ __launch_bounds__(512, 2)
void gemm128wo(const short* __restrict__ A, const short* __restrict__ W,
               const float* __restrict__ bias, float* __restrict__ out) {
    __shared__ short As[2][128 * 64];   // 32 KB
    __shared__ short Ws[2][128 * 64];   // 32 KB

    int t = threadIdx.x;
    int bid = blockIdx.x;
    int mt = bid & 31, nt = bid >> 5;
    int m0 = mt * 128, n0 = nt * 128;

    int lane = t & 63, w = t >> 6;
    int quad = lane >> 4, col = lane & 15;
    int wm = (w >> 2) * 64;
    int wn = (w & 3) * 32;

    float4v acc[4][2];
    #pragma unroll
    for (int i = 0; i < 4; i++)
        #pragma unroll
        for (int j = 0; j < 2; j++) acc[i][j] = (float4v){0, 0, 0, 0};

    int srow = t >> 3;
    int scol = ((t & 7) ^ (srow & 7)) * 8;
    const short* Ap = A + (size_t)(m0 + srow) * DMM + scol;
    const short* Wp = W + (size_t)(n0 + srow) * DMM + scol;

    #define STAGEWO(bf, tt) do { size_t kk = (size_t)(tt) * 64; \
        ASYNC16(Ap + kk,                      &As[bf][t * 8]); \
        ASYNC16(Ap + 64 * (size_t)DMM + kk,   &As[bf][4096 + t * 8]); \
        ASYNC16(Wp + kk,                      &Ws[bf][t * 8]); \
        ASYNC16(Wp + 64 * (size_t)DMM + kk,   &Ws[bf][4096 + t * 8]); \
    } while (0)

    int c7 = col & 7;

    STAGEWO(0, 0);

    for (int it = 0; it < 16; it++) {
        int cur = it & 1;
        if (it < 15) {
            STAGEWO(cur ^ 1, it + 1);
            asm volatile("s_waitcnt vmcnt(4)" ::: "memory");
        } else {
            asm volatile("s_waitcnt vmcnt(0)" ::: "memory");
        }
        __builtin_amdgcn_s_barrier();

        short8 bF[2][2];
        #pragma unroll
        for (int j = 0; j < 2; j++) {
            int rB = (wn + 16 * j + col) * 64;
            #pragma unroll
            for (int ks = 0; ks < 2; ks++)
                bF[j][ks] = *(short8*)&Ws[cur][rB + ((((ks << 2) | quad) ^ c7) << 3)];
        }

        #pragma unroll
        for (int p = 0; p < 2; p++) {
            if (p) __builtin_amdgcn_s_barrier();
            short8 aF[2][2];
            #pragma unroll
            for (int u = 0; u < 2; u++) {
                int rA = (wm + 16 * (2 * p + u) + col) * 64;
                #pragma unroll
                for (int ks = 0; ks < 2; ks++)
                    aF[u][ks] = *(short8*)&As[cur][rA + ((((ks << 2) | quad) ^ c7) << 3)];
            }
            __builtin_amdgcn_s_setprio(1);
            #pragma unroll
            for (int ks = 0; ks < 2; ks++)
                #pragma unroll
                for (int u = 0; u < 2; u++)
                    #pragma unroll
                    for (int j = 0; j < 2; j++)
                        acc[2 * p + u][j] = __builtin_amdgcn_mfma_f32_16x16x32_bf16(
                            aF[u][ks], bF[j][ks], acc[2 * p + u][j], 0, 0, 0);
            __builtin_amdgcn_s_setprio(0);
        }
        __builtin_amdgcn_s_barrier();
    }
    #undef STAGEWO

    #pragma unroll
    for (int i = 0; i < 4; i++) {
        #pragma unroll
        for (int j = 0; j < 2; j++) {
            int n = n0 + wn + 16 * j + col;
            float bn = bias[n];
            #pragma unroll
            for (int r = 0; r < 4; r++) {
                int m = m0 + wm + 16 * i + quad * 4 + r;
                out[(size_t)m * DMM + n] = acc[i][j][r] + bn;
            }
        }
    }
}

// ---------------- fused attention: band (0..1023) + global_part (1024..1279) + in-grid merge ----
// Band skips ao stores at global rows (gmap bitmap). Each (b,h) has 8 gpart blocks; each
// writes TWO sp partials (g=0,1 wave-pairs) -> counter target is 8 arrivals (old==7).
// Canonical last-block pattern: all threads __threadfence() (agent release, L2 writeback)
// before the counter; winner __threadfence() again (acquire, invalidate) before reading.
__global__ __launch_bounds__(256)
void attn_fused(const short* __restrict__ qh, const short* __restrict__ kh,
                const short* __restrict__ vh, const int* __restrict__ glist,
                const int* __restrict__ gcount, const int* __restrict__ gmap,
                short* __restrict__ ao, float* __restrict__ pl, float* __restrict__ pO,
                int* __restrict__ bcnt) {
    __shared__ __align__(16) char smem[29200];
    int t = threadIdx.x;
    int bid = blockIdx.x;
    int nG = *gcount;

    if (bid < 1024) {
        // ---------- banded attention (XCD-local, swizzled Vt, interval mask, T14 prefetch) -------
        short* Qs = (short*)smem;            // 64*72
        short* Ks = Qs + 64 * 72;            // 32*72
        short* Vt = Ks + 32 * 72;            // 64*40
        short* Ps = Vt + 64 * 40;            // 4*16*40
        int*   gjs = (int*)(Ps + 4 * 16 * 40);  // 32 ints

        int xcd = bid & 7, idx = bid >> 3;
        int gl  = idx >> 4;
        int qt  = idx & 15;
        int gid = xcd * 8 + gl;
        int z   = gid >> 4;
        int h   = gid & 15;
        int b = z >> 1, p = z & 1;
        int qq0 = qt * 64;

        const short* Qb = qh + ((size_t)(b * HH + h) * SS) * HDD;
        const short* Kb = kh + ((size_t)(b * HH + h) * SS) * HDD;
        const short* Vb = vh + ((size_t)(b * HH + h) * SS) * HDD;

        int row8 = t >> 3;
        int dim8 = (t & 7) * 8;

        #pragma unroll
        for (int rr = 0; rr < 2; rr++) {
            int row = rr * 32 + row8;
            int i = 2 * (qq0 + row) + p;
            short8 qv = *(const short8*)(Qb + (size_t)i * HDD + dim8);
            *(short8*)&Qs[row * 72 + dim8] = qv;
        }
        if (t < 32) gjs[t] = (t < nG) ? glist[t] : -1000000;
        __syncthreads();

        int lane = t & 63, w = t >> 6;
        int quad = lane >> 4, col = lane & 15;

        short8 qf0 = *(short8*)&Qs[(16 * w + col) * 72 + quad * 8];
        short8 qf1 = *(short8*)&Qs[(16 * w + col) * 72 + 32 + quad * 8];

        float4v O0 = {0,0,0,0}, O1 = {0,0,0,0}, O2 = {0,0,0,0}, O3 = {0,0,0,0};
        float lst[4] = {0.f, 0.f, 0.f, 0.f};

        short8 kvP, vvP, kvN, vvN;
        {
            int srow = 2 * (qq0 - 256 + row8) + p;
            srow = srow < 0 ? 0 : (srow > SS - 1 ? SS - 1 : srow);
            kvP = *(const short8*)(Kb + (size_t)srow * HDD + dim8);
            vvP = *(const short8*)(Vb + (size_t)srow * HDD + dim8);
        }

        for (int c = 0; c < 19; c++) {
            __syncthreads();
            *(short8*)&Ks[row8 * 72 + dim8] = kvP;
            #pragma unroll
            for (int j = 0; j < 8; j++) {
                int d = dim8 + j;
                Vt[VSL(d, row8)] = vvP[j];
            }
            if (c < 18) {
                int cn = c + 1;
                int ch0n = qq0 - 256 + cn * 32;
                int srow;
                if (cn < 18) srow = 2 * (ch0n + row8) + p;
                else         srow = (row8 < nG) ? gjs[row8] : 0;
                srow = srow < 0 ? 0 : (srow > SS - 1 ? SS - 1 : srow);
                kvN = *(const short8*)(Kb + (size_t)srow * HDD + dim8);
                vvN = *(const short8*)(Vb + (size_t)srow * HDD + dim8);
            }
            __syncthreads();

            int ch0 = qq0 - 256 + c * 32;

            short8 kA0 = *(short8*)&Ks[col * 72 + quad * 8];
            short8 kA1 = *(short8*)&Ks[col * 72 + 32 + quad * 8];
            short8 kB0 = *(short8*)&Ks[(16 + col) * 72 + quad * 8];
            short8 kB1 = *(short8*)&Ks[(16 + col) * 72 + 32 + quad * 8];
            float4v sA = {0,0,0,0}, sB = {0,0,0,0};
            sA = __builtin_amdgcn_mfma_f32_16x16x32_bf16(qf0, kA0, sA, 0, 0, 0);
            sA = __builtin_amdgcn_mfma_f32_16x16x32_bf16(qf1, kA1, sA, 0, 0, 0);
            sB = __builtin_amdgcn_mfma_f32_16x16x32_bf16(qf0, kB0, sB, 0, 0, 0);
            sB = __builtin_amdgcn_mfma_f32_16x16x32_bf16(qf1, kB1, sB, 0, 0, 0);

            if (c < 18) {
                int nlo = -ch0;
                int nhi = 1023 - ch0;
                #pragma unroll
                for (int r = 0; r < 4; r++) {
                    int qq = qq0 + 16 * w + quad * 4 + r;
                    int u  = qq - ch0;
                    int lo = max(u - 256, nlo);
                    int hi = min(u + 256, nhi);
                    bool vA = (col >= lo) && (col <= hi);
                    bool vB = (col + 16 >= lo) && (col + 16 <= hi);
                    float pa = vA ? exp2f(sA[r] * SCALE2) : 0.f;
                    float pb = vB ? exp2f(sB[r] * SCALE2) : 0.f;
                    lst[r] += pa + pb;
                    Ps[(w * 16 + quad * 4 + r) * 40 + col]      = f2bf(pa);
                    Ps[(w * 16 + quad * 4 + r) * 40 + col + 16] = f2bf(pb);
                }
            } else {
                #pragma unroll
                for (int r = 0; r < 4; r++) {
                    int qq = qq0 + 16 * w + quad * 4 + r;
                    int i = 2 * qq + p;
                    int jA = gjs[col], jB = gjs[col + 16];
                    int dA = jA - i, dB = jB - i;
                    int aA = dA < 0 ? -dA : dA;
                    int aB = dB < 0 ? -dB : dB;
                    bool vA = (jA >= 0) && !((aA <= 512) && ((dA & 1) == 0));
                    bool vB = (jB >= 0) && !((aB <= 512) && ((dB & 1) == 0));
                    float pa = vA ? exp2f(sA[r] * SCALE2) : 0.f;
                    float pb = vB ? exp2f(sB[r] * SCALE2) : 0.f;
                    lst[r] += pa + pb;
                    Ps[(w * 16 + quad * 4 + r) * 40 + col]      = f2bf(pa);
                    Ps[(w * 16 + quad * 4 + r) * 40 + col + 16] = f2bf(pb);
                }
            }
            asm volatile("s_waitcnt lgkmcnt(0)" ::: "memory");

            short8 pf  = *(short8*)&Ps[(w * 16 + col) * 40 + quad * 8];
            short8 vf0 = *(short8*)&Vt[(col) * 40 + ((quad ^ ((col >> 3) & 3)) << 3)];
            short8 vf1 = *(short8*)&Vt[(16 + col) * 40 + ((quad ^ (((16 + col) >> 3) & 3)) << 3)];
            short8 vf2 = *(short8*)&Vt[(32 + col) * 40 + ((quad ^ (((32 + col) >> 3) & 3)) << 3)];
            short8 vf3 = *(short8*)&Vt[(48 + col) * 40 + ((quad ^ (((48 + col) >> 3) & 3)) << 3)];
            O0 = __builtin_amdgcn_mfma_f32_16x16x32_bf16(pf, vf0, O0, 0, 0, 0);
            O1 = __builtin_amdgcn_mfma_f32_16x16x32_bf16(pf, vf1, O1, 0, 0, 0);
            O2 = __builtin_amdgcn_mfma_f32_16x16x32_bf16(pf, vf2, O2, 0, 0, 0);
            O3 = __builtin_amdgcn_mfma_f32_16x16x32_bf16(pf, vf3, O3, 0, 0, 0);

            kvP = kvN; vvP = vvN;
        }

        #pragma unroll
        for (int r = 0; r < 4; r++) {
            float l = lst[r];
            #pragma unroll
            for (int mk = 1; mk < 16; mk <<= 1) l += __shfl_xor(l, mk);
            float inv = 1.0f / l;
            int q = 16 * w + quad * 4 + r;
            int i = 2 * (qq0 + q) + p;
            if (!gmap[i]) {   // global rows are written by the in-grid merge instead
                short* dst = ao + ((size_t)b * SS + i) * DMM + h * HDD;
                dst[col]      = f2bf(O0[r] * inv);
                dst[col + 16] = f2bf(O1[r] * inv);
                dst[col + 32] = f2bf(O2[r] * inv);
                dst[col + 48] = f2bf(O3[r] * inv);
            }
        }
    } else {
        // ---------- global rows: split-K MFMA partials (no-max softmax) + last-block merge -------
        short* Qs  = (short*)smem;            // 32*72
        short* Ksf = Qs + 32 * 72;            // 2 x 32*72
        short* Vtf = Ksf + 2 * 32 * 72;       // 2 x 64*40
        short* Ps  = Vtf + 2 * 64 * 40;       // 4*16*40
        int* sflag = (int*)(smem + 29184);

        int r0 = bid - 1024;
        int s = r0 & 7, h = (r0 >> 3) & 15, b = r0 >> 7;

        const short* Qb = qh + ((size_t)(b * HH + h) * SS) * HDD;
        const short* Kb = kh + ((size_t)(b * HH + h) * SS) * HDD;
        const short* Vb = vh + ((size_t)(b * HH + h) * SS) * HDD;

        int row8 = t >> 3, dim8 = (t & 7) * 8;
        {
            int cq = row8 < nG ? row8 : 0;
            int src = glist[cq];
            short8 qv = *(const short8*)(Qb + (size_t)src * HDD + dim8);
            *(short8*)&Qs[row8 * 72 + dim8] = qv;
        }
        __syncthreads();

        int lane = t & 63, w = t >> 6;
        int quad = lane >> 4, col = lane & 15;
        int g = w >> 1, qt = w & 1;

        short8 qf0 = *(short8*)&Qs[(qt * 16 + col) * 72 + quad * 8];
        short8 qf1 = *(short8*)&Qs[(qt * 16 + col) * 72 + 32 + quad * 8];

        float4v O0 = {0,0,0,0}, O1 = {0,0,0,0}, O2 = {0,0,0,0}, O3 = {0,0,0,0};
        float lst[4] = {0.f, 0.f, 0.f, 0.f};

        int js0 = s * 256;
        for (int it = 0; it < 4; it++) {
            __syncthreads();
            int r64 = t >> 2, dimb = (t & 3) * 16;
            int j = js0 + it * 64 + r64;
            const short* kp = Kb + (size_t)j * HDD + dimb;
            const short* vp = Vb + (size_t)j * HDD + dimb;
            short8 k0 = *(const short8*)kp, k1 = *(const short8*)(kp + 8);
            short8 v0 = *(const short8*)vp, v1 = *(const short8*)(vp + 8);
            int half = r64 >> 5, r32 = r64 & 31;
            short* Ksh = Ksf + half * (32 * 72);
            short* Vth = Vtf + half * (64 * 40);
            *(short8*)&Ksh[r32 * 72 + dimb]     = k0;
            *(short8*)&Ksh[r32 * 72 + dimb + 8] = k1;
            #pragma unroll
            for (int u = 0; u < 8; u++) {
                int d = dimb + u;
                Vth[VSL(d, r32)] = v0[u];
            }
            #pragma unroll
            for (int u = 0; u < 8; u++) {
                int d = dimb + 8 + u;
                Vth[VSL(d, r32)] = v1[u];
            }
            __syncthreads();

            short* Ksg = Ksf + g * (32 * 72);
            short* Vtg = Vtf + g * (64 * 40);
            short8 kA0 = *(short8*)&Ksg[col * 72 + quad * 8];
            short8 kA1 = *(short8*)&Ksg[col * 72 + 32 + quad * 8];
            short8 kB0 = *(short8*)&Ksg[(16 + col) * 72 + quad * 8];
            short8 kB1 = *(short8*)&Ksg[(16 + col) * 72 + 32 + quad * 8];
            float4v sA = {0,0,0,0}, sB = {0,0,0,0};
            sA = __builtin_amdgcn_mfma_f32_16x16x32_bf16(qf0, kA0, sA, 0, 0, 0);
            sA = __builtin_amdgcn_mfma_f32_16x16x32_bf16(qf1, kA1, sA, 0, 0, 0);
            sB = __builtin_amdgcn_mfma_f32_16x16x32_bf16(qf0, kB0, sB, 0, 0, 0);
            sB = __builtin_amdgcn_mfma_f32_16x16x32_bf16(qf1, kB1, sB, 0, 0, 0);

            #pragma unroll
            for (int r = 0; r < 4; r++) {
                float pa = exp2f(sA[r] * SCALE2);
                float pb = exp2f(sB[r] * SCALE2);
                lst[r] += pa + pb;
                Ps[(w * 16 + quad * 4 + r) * 40 + col]      = f2bf(pa);
                Ps[(w * 16 + quad * 4 + r) * 40 + col + 16] = f2bf(pb);
            }
            asm volatile("s_waitcnt lgkmcnt(0)" ::: "memory");

            short8 pf  = *(short8*)&Ps[(w * 16 + col) * 40 + quad * 8];
            short8 vf0 = *(short8*)&Vtg[(col) * 40 + ((quad ^ ((col >> 3) & 3)) << 3)];
            short8 vf1 = *(short8*)&Vtg[(16 + col) * 40 + ((quad ^ (((16 + col) >> 3) & 3)) << 3)];
            short8 vf2 = *(short8*)&Vtg[(32 + col) * 40 + ((quad ^ (((32 + col) >> 3) & 3)) << 3)];
            short8 vf3 = *(short8*)&Vtg[(48 + col) * 40 + ((quad ^ (((48 + col) >> 3) & 3)) << 3)];
            O0 = __builtin_amdgcn_mfma_f32_16x16x32_bf16(pf, vf0, O0, 0, 0, 0);
            O1 = __builtin_amdgcn_mfma_f32_16x16x32_bf16(pf, vf1, O1, 0, 0, 0);
            O2 = __builtin_amdgcn_mfma_f32_16x16x32_bf16(pf, vf2, O2, 0, 0, 0);
            O3 = __builtin_amdgcn_mfma_f32_16x16x32_bf16(pf, vf3, O3, 0, 0, 0);
        }

        int sp = s * 2 + g;
        size_t base = ((size_t)(b * HH + h) * 16 + sp) * 32;
        #pragma unroll
        for (int r = 0; r < 4; r++) {
            float l = lst[r];
            #pragma unroll
            for (int mk = 1; mk < 16; mk <<= 1) l += __shfl_xor(l, mk);
            int q = qt * 16 + quad * 4 + r;
            if (col == 0) pl[base + q] = l;
            float* Od = pO + (base + q) * 64;
            Od[col]      = O0[r];
            Od[col + 16] = O1[r];
            Od[col + 32] = O2[r];
            Od[col + 48] = O3[r];
        }

        // -------- 8th arriver (of this (b,h)'s 8 blocks) merges 16 partials, writes ao --------
        __threadfence();   // agent-scope release: this block's partials visible device-wide
        __syncthreads();
        if (t == 0) {
            int bh = b * HH + h;
            *sflag = atomicAdd(&bcnt[bh], 1);   // device-scope by default (m20)
        }
        __syncthreads();
        if (*sflag == 7) {
            __threadfence();   // acquire side: discard stale cached partials
            int d = t & 63, qg = t >> 6;
            size_t bh2 = ((size_t)(b * HH + h) * 16) * 32;
            for (int q2 = qg; q2 < nG; q2 += 4) {
                float L = 0.f, acc2 = 0.f;
                #pragma unroll
                for (int sp2 = 0; sp2 < 16; sp2++) {
                    L    += pl[bh2 + sp2 * 32 + q2];
                    acc2 += pO[(bh2 + sp2 * 32 + q2) * 64 + d];
                }
                int i = glist[q2];
                ao[((size_t)b * SS + i) * DMM + h * HDD + d] = f2bf(acc2 / L);
            }
        }
    }
}

extern "C" void kernel_launch(void* const* d_in, const int* in_sizes, int n_in,
                              void* d_out, int out_size, void* d_ws, size_t ws_size,
                              hipStream_t stream) {
    const float* q  = (const float*)d_in[0];
    const float* k  = (const float*)d_in[1];
    const float* v  = (const float*)d_in[2];
    const float* Wq = (const float*)d_in[3];
    const float* Wk = (const float*)d_in[4];
    const float* Wv = (const float*)d_in[5];
    const float* Wo = (const float*)d_in[6];
    const float* bq = (const float*)d_in[7];
    const float* bk = (const float*)d_in[8];
    const float* bv = (const float*)d_in[9];
    const float* bo = (const float*)d_in[10];
    const int* gidx = (const int*)d_in[11];
    float* out = (float*)d_out;

    // ws (64.03 MB): 32KB hdr | qh,kh,vh,ao bf16 8MB ea | wbf 8MB | abf 24MB (aliased by pl+pO)
    const size_t NE = (size_t)BB * SS * DMM;   // 4M
    const size_t WE = (size_t)DMM * DMM;       // 1M
    int*   g      = (int*)d_ws;
    int*   glist  = g + SS;
    int*   gcount = glist + SS;
    int*   bcnt   = gcount + 1;            // 32 merge counters (one per b,h)
    short* qh     = (short*)((char*)d_ws + 32768);
    short* kh     = qh + NE;
    short* vh     = kh + NE;
    short* ao     = vh + NE;
    short* wbf    = ao + NE;
    short* wo     = wbf + 3 * WE;
    short* abf    = wbf + 4 * WE;          // dead after QKV gemm
    float* pl     = (float*)abf;           // alias: written by attn_fused gpart branch (later)
    float* pO     = pl + 16384;

    convert_flat<<<8193, 256, 0, stream>>>(q, k, v, Wq, Wk, Wv, Wo, abf, wbf,
                                           gidx, g, glist, gcount, bcnt);

    dim3 gq(64, 3);    // batched QKV, 256x256 tiles: 192 blocks, 512 threads
    gemm256<1, 1><<<gq, 512, 0, stream>>>(abf, wbf, bq, bk, bv, qh, kh, vh);

    attn_fused<<<1280, 256, 0, stream>>>(qh, kh, vh, glist, gcount, g, ao, pl, pO, bcnt);

    gemm128wo<<<256, 512, 0, stream>>>(ao, wo, bo, out);   // Wo: full CU coverage
}

// Round 9
// 226.362 us; speedup vs baseline: 1.1258x; 1.1258x over previous
//
#include <hip/hip_runtime.h>
#include <hip/hip_bf16.h>
#include <math.h>

#define BB 2
#define SS 2048
#define DMM 1024
#define HH 16
#define HDD 64
#define NGLOB 32
#define MM 4096   // B*S
#define SCALE2 0.18033688f   // 0.125 * log2(e): exp(s/8) == exp2(s*SCALE2)

typedef __attribute__((ext_vector_type(8))) short short8;
typedef __attribute__((ext_vector_type(4))) float float4v;

__device__ __forceinline__ short f2bf(float f) {
    union { float f; unsigned u; } x; x.f = f;
    unsigned r = (x.u + 0x7fffu + ((x.u >> 16) & 1u)) >> 16;  // RNE
    return (short)r;
}

// async 16B global->LDS (m97 path). LDS dest = wave-uniform base + lane*16.
#define ASYNC16(gp, lp) __builtin_amdgcn_global_load_lds( \
    (__attribute__((address_space(1))) void*)(gp), \
    (__attribute__((address_space(3))) void*)(lp), 16, 0, 0)

// Vt slot swizzle: key-chunk XORed with dim-derived tag -> breaks the
// dim*stride==0 (mod 32 banks) collapse on transpose stores (16-way -> 4-way).
#define VSL(dim, key) ((dim) * 40 + (((((key) >> 3) ^ (((dim) >> 3) & 3)) << 3) | ((key) & 7)))

// ---------------- flat convert fp32->bf16 + setup_globals (block 8192) ----------------
// Exact 1D grid (8193 blocks): q 0..2047, k 2048..4095, v 4096..6143, weights 6144..8191
// (512 each), setup 8192. No idle blocks.
__global__ __launch_bounds__(256)
void convert_flat(const float* __restrict__ q, const float* __restrict__ k,
                  const float* __restrict__ v,
                  const float* __restrict__ w0, const float* __restrict__ w1,
                  const float* __restrict__ w2, const float* __restrict__ w3,
                  short* __restrict__ abf, short* __restrict__ wbf,
                  const int* __restrict__ gidx, int* __restrict__ g,
                  int* __restrict__ glist, int* __restrict__ gcount) {
    int bid = blockIdx.x;
    int t = threadIdx.x;
    if (bid == 6144 + 2048) {          // setup_globals
        for (int i = t; i < SS; i += 256) g[i] = 0;
        if (t == 0) *gcount = 0;
        __syncthreads();
        if (t < NGLOB) {
            int j = gidx[t];
            if (j >= 0 && j < SS) g[j] = 1;
        }
        __syncthreads();
        for (int j = t; j < SS; j += 256) {
            if (g[j]) {
                int p = atomicAdd(gcount, 1);
                glist[p] = j;
            }
        }
        return;
    }
    const float* src;
    short* dst;
    if (bid < 6144) {                  // q/k/v: 4M elems each = 2048 blocks each
        int z = bid >> 11;
        size_t off = ((size_t)(bid & 2047) << 11) + (size_t)t * 8;
        src = ((z == 0) ? q : (z == 1) ? k : v) + off;
        dst = abf + ((size_t)z << 22) + off;
    } else {                           // weights: 1M elems each = 512 blocks each
        int y = (bid - 6144) >> 9;
        size_t off = ((size_t)((bid - 6144) & 511) << 11) + (size_t)t * 8;
        src = ((y == 0) ? w0 : (y == 1) ? w1 : (y == 2) ? w2 : w3) + off;
        dst = wbf + ((size_t)y << 20) + off;
    }
    float4 a = *(const float4*)(src);
    float4 b = *(const float4*)(src + 4);
    short8 s;
    s[0]=f2bf(a.x); s[1]=f2bf(a.y); s[2]=f2bf(a.z); s[3]=f2bf(a.w);
    s[4]=f2bf(b.x); s[5]=f2bf(b.y); s[6]=f2bf(b.z); s[7]=f2bf(b.w);
    *(short8*)dst = s;
}

// ---------------- 256x256/BK=64 MFMA GEMM: true 8-phase interleave (R6-verified) ----------------
// UNCHANGED from R6 (protect the win).
template<int OBF, int HEADSPLIT>
__global__ __launch_bounds__(512, 2)
void gemm256(const short* __restrict__ Abase, const short* __restrict__ Wbase,
             const float* __restrict__ b0, const float* __restrict__ b1,
             const float* __restrict__ b2,
             void* __restrict__ O0p, void* __restrict__ O1p, void* __restrict__ O2p) {
    __shared__ short As[2][256 * 64];   // 64 KB
    __shared__ short Ws[2][256 * 64];   // 64 KB

    int t = threadIdx.x;
    int z = blockIdx.y;
    const short* A    = Abase + (size_t)z * ((size_t)MM * DMM);
    const short* W    = Wbase + (size_t)z * ((size_t)DMM * DMM);
    const float* bias = (z == 0) ? b0 : (z == 1) ? b1 : b2;
    void* outp        = (z == 0) ? O0p : (z == 1) ? O1p : O2p;

    int bid = blockIdx.x;
    int mt = bid & 15, nt = bid >> 4;   // bid%8 == mt%8: nt-blocks of one mt share an XCD
    int m0 = mt * 256, n0 = nt * 256;

    int lane = t & 63, w = t >> 6;
    int quad = lane >> 4, col = lane & 15;
    int wm = (w >> 2) * 128;
    int wn = (w & 3) * 64;

    float4v acc[8][4];
    #pragma unroll
    for (int i = 0; i < 8; i++)
        #pragma unroll
        for (int j = 0; j < 4; j++) acc[i][j] = (float4v){0, 0, 0, 0};

    int srow = t >> 3;
    int scol = ((t & 7) ^ (srow & 7)) * 8;
    const short* Ap = A + (size_t)(m0 + srow) * DMM + scol;
    const short* Wp = W + (size_t)(n0 + srow) * DMM + scol;

    #define ST_W(bf, tt, h) ASYNC16(Wp + (size_t)(h) * 64 * DMM + (size_t)(tt) * 64, \
                                    &Ws[bf][(h) * 4096 + t * 8])
    #define ST_A(bf, tt, h) ASYNC16(Ap + (size_t)(h) * 64 * DMM + (size_t)(tt) * 64, \
                                    &As[bf][(h) * 4096 + t * 8])

    int c7 = col & 7;

    // prologue: stage step 0 in counted order, certify idx 0..5
    ST_W(0, 0, 0); ST_W(0, 0, 1); ST_W(0, 0, 2); ST_W(0, 0, 3);
    ST_A(0, 0, 0); ST_A(0, 0, 2); ST_A(0, 0, 1); ST_A(0, 0, 3);
    asm volatile("s_waitcnt vmcnt(2)" ::: "memory");
    __builtin_amdgcn_s_barrier();

    for (int it = 0; it < 16; it++) {
        int cur = it & 1, nb = cur ^ 1;
        bool pf = (it < 15);

        short8 bF[4][2];
        #pragma unroll
        for (int j = 0; j < 4; j++) {
            int rB = (wn + 16 * j + col) * 64;
            #pragma unroll
            for (int ks = 0; ks < 2; ks++)
                bF[j][ks] = *(short8*)&Ws[cur][rB + ((((ks << 2) | quad) ^ c7) << 3)];
        }

        #pragma unroll
        for (int p = 0; p < 4; p++) {
            short8 aF[2][2];
            #pragma unroll
            for (int u = 0; u < 2; u++) {
                int rA = (wm + 16 * (2 * p + u) + col) * 64;
                #pragma unroll
                for (int ks = 0; ks < 2; ks++)
                    aF[u][ks] = *(short8*)&As[cur][rA + ((((ks << 2) | quad) ^ c7) << 3)];
            }
            if (pf) {
                if (p == 0)      { ST_W(nb, it + 1, 0); ST_W(nb, it + 1, 1); }
                else if (p == 1) { ST_W(nb, it + 1, 2); ST_W(nb, it + 1, 3); }
                else if (p == 2) { ST_A(nb, it + 1, 0); ST_A(nb, it + 1, 2); }
                else             { ST_A(nb, it + 1, 1); ST_A(nb, it + 1, 3); }
            }
            __builtin_amdgcn_s_barrier();
            __builtin_amdgcn_s_setprio(1);
            #pragma unroll
            for (int ks = 0; ks < 2; ks++)
                #pragma unroll
                for (int u = 0; u < 2; u++)
                    #pragma unroll
                    for (int j = 0; j < 4; j++)
                        acc[2 * p + u][j] = __builtin_amdgcn_mfma_f32_16x16x32_bf16(
                            aF[u][ks], bF[j][ks], acc[2 * p + u][j], 0, 0, 0);
            __builtin_amdgcn_s_setprio(0);
            if (p == 1) {
                if (pf) asm volatile("s_waitcnt vmcnt(4)" ::: "memory");
                else    asm volatile("s_waitcnt vmcnt(0)" ::: "memory");
            }
            if (p == 3 && pf)
                asm volatile("s_waitcnt vmcnt(2)" ::: "memory");
            __builtin_amdgcn_s_barrier();
        }
    }
    #undef ST_W
    #undef ST_A

    #pragma unroll
    for (int i = 0; i < 8; i++) {
        #pragma unroll
        for (int j = 0; j < 4; j++) {
            int n = n0 + wn + 16 * j + col;
            float bn = bias[n];
            #pragma unroll
            for (int r = 0; r < 4; r++) {
                int m = m0 + wm + 16 * i + quad * 4 + r;
                float val = acc[i][j][r] + bn;
                size_t idx;
                if (HEADSPLIT) {
                    int b = m >> 11;
                    int s = m & 2047;
                    int h = n >> 6;
                    int hd = n & 63;
                    idx = (((size_t)b * HH + h) * SS + s) * HDD + hd;
                } else {
                    idx = (size_t)m * DMM + n;
                }
                if (OBF) ((short*)outp)[idx] = f2bf(val);
                else     ((float*)outp)[idx] = val;
            }
        }
    }
}

// ---------------- Wo GEMM: 128x128/BK=64, 512 thr, T2 swizzle + counted vmcnt + T5 --------------
// UNCHANGED from R5/R6. 256 blocks = full CU coverage.
__global__ __launch_bounds__(512, 2)
void gemm128wo(const short* __restrict__ A, const short* __restrict__ W,
               const float* __restrict__ bias, float* __restrict__ out) {
    __shared__ short As[2][128 * 64];   // 32 KB
    __shared__ short Ws[2][128 * 64];   // 32 KB

    int t = threadIdx.x;
    int bid = blockIdx.x;
    int mt = bid & 31, nt = bid >> 5;
    int m0 = mt * 128, n0 = nt * 128;

    int lane = t & 63, w = t >> 6;
    int quad = lane >> 4, col = lane & 15;
    int wm = (w >> 2) * 64;
    int wn = (w & 3) * 32;

    float4v acc[4][2];
    #pragma unroll
    for (int i = 0; i < 4; i++)
        #pragma unroll
        for (int j = 0; j < 2; j++) acc[i][j] = (float4v){0, 0, 0, 0};

    int srow = t >> 3;
    int scol = ((t & 7) ^ (srow & 7)) * 8;
    const short* Ap = A + (size_t)(m0 + srow) * DMM + scol;
    const short* Wp = W + (size_t)(n0 + srow) * DMM + scol;

    #define STAGEWO(bf, tt) do { size_t kk = (size_t)(tt) * 64; \
        ASYNC16(Ap + kk,                      &As[bf][t * 8]); \
        ASYNC16(Ap + 64 * (size_t)DMM + kk,   &As[bf][4096 + t * 8]); \
        ASYNC16(Wp + kk,                      &Ws[bf][t * 8]); \
        ASYNC16(Wp + 64 * (size_t)DMM + kk,   &Ws[bf][4096 + t * 8]); \
    } while (0)

    int c7 = col & 7;

    STAGEWO(0, 0);

    for (int it = 0; it < 16; it++) {
        int cur = it & 1;
        if (it < 15) {
            STAGEWO(cur ^ 1, it + 1);
            asm volatile("s_waitcnt vmcnt(4)" ::: "memory");
        } else {
            asm volatile("s_waitcnt vmcnt(0)" ::: "memory");
        }
        __builtin_amdgcn_s_barrier();

        short8 bF[2][2];
        #pragma unroll
        for (int j = 0; j < 2; j++) {
            int rB = (wn + 16 * j + col) * 64;
            #pragma unroll
            for (int ks = 0; ks < 2; ks++)
                bF[j][ks] = *(short8*)&Ws[cur][rB + ((((ks << 2) | quad) ^ c7) << 3)];
        }

        #pragma unroll
        for (int p = 0; p < 2; p++) {
            if (p) __builtin_amdgcn_s_barrier();
            short8 aF[2][2];
            #pragma unroll
            for (int u = 0; u < 2; u++) {
                int rA = (wm + 16 * (2 * p + u) + col) * 64;
                #pragma unroll
                for (int ks = 0; ks < 2; ks++)
                    aF[u][ks] = *(short8*)&As[cur][rA + ((((ks << 2) | quad) ^ c7) << 3)];
            }
            __builtin_amdgcn_s_setprio(1);
            #pragma unroll
            for (int ks = 0; ks < 2; ks++)
                #pragma unroll
                for (int u = 0; u < 2; u++)
                    #pragma unroll
                    for (int j = 0; j < 2; j++)
                        acc[2 * p + u][j] = __builtin_amdgcn_mfma_f32_16x16x32_bf16(
                            aF[u][ks], bF[j][ks], acc[2 * p + u][j], 0, 0, 0);
            __builtin_amdgcn_s_setprio(0);
        }
        __builtin_amdgcn_s_barrier();
    }
    #undef STAGEWO

    #pragma unroll
    for (int i = 0; i < 4; i++) {
        #pragma unroll
        for (int j = 0; j < 2; j++) {
            int n = n0 + wn + 16 * j + col;
            float bn = bias[n];
            #pragma unroll
            for (int r = 0; r < 4; r++) {
                int m = m0 + wm + 16 * i + quad * 4 + r;
                out[(size_t)m * DMM + n] = acc[i][j][r] + bn;
            }
        }
    }
}

// ---------------- fused attention: band (0..1023) + whole-row global blocks (1024..1055) --------
// NO cross-block communication anywhere -> no fences (R8's __threadfence compiled to per-XCD
// L2 writeback/invalidate and poisoned band's L2 locality: 97us vs <40).
// gpart: ONE block per (b,h) loops all 2048 keys (32 chunks of the staged inner body),
// accumulates O/L in registers, combines the two g-half waves through LDS, writes ao
// global rows directly. Band skips global rows (gmap) -> disjoint writers, orderless.
__global__ __launch_bounds__(256)
void attn_fused(const short* __restrict__ qh, const short* __restrict__ kh,
                const short* __restrict__ vh, const int* __restrict__ glist,
                const int* __restrict__ gcount, const int* __restrict__ gmap,
                short* __restrict__ ao) {
    __shared__ __align__(16) char smem[29200];
    int t = threadIdx.x;
    int bid = blockIdx.x;
    int nG = *gcount;

    if (bid < 1024) {
        // ---------- banded attention (XCD-local, swizzled Vt, interval mask, T14 prefetch) -------
        short* Qs = (short*)smem;            // 64*72
        short* Ks = Qs + 64 * 72;            // 32*72
        short* Vt = Ks + 32 * 72;            // 64*40
        short* Ps = Vt + 64 * 40;            // 4*16*40
        int*   gjs = (int*)(Ps + 4 * 16 * 40);  // 32 ints

        int xcd = bid & 7, idx = bid >> 3;
        int gl  = idx >> 4;
        int qt  = idx & 15;
        int gid = xcd * 8 + gl;
        int z   = gid >> 4;
        int h   = gid & 15;
        int b = z >> 1, p = z & 1;
        int qq0 = qt * 64;

        const short* Qb = qh + ((size_t)(b * HH + h) * SS) * HDD;
        const short* Kb = kh + ((size_t)(b * HH + h) * SS) * HDD;
        const short* Vb = vh + ((size_t)(b * HH + h) * SS) * HDD;

        int row8 = t >> 3;
        int dim8 = (t & 7) * 8;

        #pragma unroll
        for (int rr = 0; rr < 2; rr++) {
            int row = rr * 32 + row8;
            int i = 2 * (qq0 + row) + p;
            short8 qv = *(const short8*)(Qb + (size_t)i * HDD + dim8);
            *(short8*)&Qs[row * 72 + dim8] = qv;
        }
        if (t < 32) gjs[t] = (t < nG) ? glist[t] : -1000000;
        __syncthreads();

        int lane = t & 63, w = t >> 6;
        int quad = lane >> 4, col = lane & 15;

        short8 qf0 = *(short8*)&Qs[(16 * w + col) * 72 + quad * 8];
        short8 qf1 = *(short8*)&Qs[(16 * w + col) * 72 + 32 + quad * 8];

        float4v O0 = {0,0,0,0}, O1 = {0,0,0,0}, O2 = {0,0,0,0}, O3 = {0,0,0,0};
        float lst[4] = {0.f, 0.f, 0.f, 0.f};

        short8 kvP, vvP, kvN, vvN;
        {
            int srow = 2 * (qq0 - 256 + row8) + p;
            srow = srow < 0 ? 0 : (srow > SS - 1 ? SS - 1 : srow);
            kvP = *(const short8*)(Kb + (size_t)srow * HDD + dim8);
            vvP = *(const short8*)(Vb + (size_t)srow * HDD + dim8);
        }

        for (int c = 0; c < 19; c++) {
            __syncthreads();
            *(short8*)&Ks[row8 * 72 + dim8] = kvP;
            #pragma unroll
            for (int j = 0; j < 8; j++) {
                int d = dim8 + j;
                Vt[VSL(d, row8)] = vvP[j];
            }
            if (c < 18) {
                int cn = c + 1;
                int ch0n = qq0 - 256 + cn * 32;
                int srow;
                if (cn < 18) srow = 2 * (ch0n + row8) + p;
                else         srow = (row8 < nG) ? gjs[row8] : 0;
                srow = srow < 0 ? 0 : (srow > SS - 1 ? SS - 1 : srow);
                kvN = *(const short8*)(Kb + (size_t)srow * HDD + dim8);
                vvN = *(const short8*)(Vb + (size_t)srow * HDD + dim8);
            }
            __syncthreads();

            int ch0 = qq0 - 256 + c * 32;

            short8 kA0 = *(short8*)&Ks[col * 72 + quad * 8];
            short8 kA1 = *(short8*)&Ks[col * 72 + 32 + quad * 8];
            short8 kB0 = *(short8*)&Ks[(16 + col) * 72 + quad * 8];
            short8 kB1 = *(short8*)&Ks[(16 + col) * 72 + 32 + quad * 8];
            float4v sA = {0,0,0,0}, sB = {0,0,0,0};
            sA = __builtin_amdgcn_mfma_f32_16x16x32_bf16(qf0, kA0, sA, 0, 0, 0);
            sA = __builtin_amdgcn_mfma_f32_16x16x32_bf16(qf1, kA1, sA, 0, 0, 0);
            sB = __builtin_amdgcn_mfma_f32_16x16x32_bf16(qf0, kB0, sB, 0, 0, 0);
            sB = __builtin_amdgcn_mfma_f32_16x16x32_bf16(qf1, kB1, sB, 0, 0, 0);

            if (c < 18) {
                int nlo = -ch0;
                int nhi = 1023 - ch0;
                #pragma unroll
                for (int r = 0; r < 4; r++) {
                    int qq = qq0 + 16 * w + quad * 4 + r;
                    int u  = qq - ch0;
                    int lo = max(u - 256, nlo);
                    int hi = min(u + 256, nhi);
                    bool vA = (col >= lo) && (col <= hi);
                    bool vB = (col + 16 >= lo) && (col + 16 <= hi);
                    float pa = vA ? exp2f(sA[r] * SCALE2) : 0.f;
                    float pb = vB ? exp2f(sB[r] * SCALE2) : 0.f;
                    lst[r] += pa + pb;
                    Ps[(w * 16 + quad * 4 + r) * 40 + col]      = f2bf(pa);
                    Ps[(w * 16 + quad * 4 + r) * 40 + col + 16] = f2bf(pb);
                }
            } else {
                #pragma unroll
                for (int r = 0; r < 4; r++) {
                    int qq = qq0 + 16 * w + quad * 4 + r;
                    int i = 2 * qq + p;
                    int jA = gjs[col], jB = gjs[col + 16];
                    int dA = jA - i, dB = jB - i;
                    int aA = dA < 0 ? -dA : dA;
                    int aB = dB < 0 ? -dB : dB;
                    bool vA = (jA >= 0) && !((aA <= 512) && ((dA & 1) == 0));
                    bool vB = (jB >= 0) && !((aB <= 512) && ((dB & 1) == 0));
                    float pa = vA ? exp2f(sA[r] * SCALE2) : 0.f;
                    float pb = vB ? exp2f(sB[r] * SCALE2) : 0.f;
                    lst[r] += pa + pb;
                    Ps[(w * 16 + quad * 4 + r) * 40 + col]      = f2bf(pa);
                    Ps[(w * 16 + quad * 4 + r) * 40 + col + 16] = f2bf(pb);
                }
            }
            asm volatile("s_waitcnt lgkmcnt(0)" ::: "memory");

            short8 pf  = *(short8*)&Ps[(w * 16 + col) * 40 + quad * 8];
            short8 vf0 = *(short8*)&Vt[(col) * 40 + ((quad ^ ((col >> 3) & 3)) << 3)];
            short8 vf1 = *(short8*)&Vt[(16 + col) * 40 + ((quad ^ (((16 + col) >> 3) & 3)) << 3)];
            short8 vf2 = *(short8*)&Vt[(32 + col) * 40 + ((quad ^ (((32 + col) >> 3) & 3)) << 3)];
            short8 vf3 = *(short8*)&Vt[(48 + col) * 40 + ((quad ^ (((48 + col) >> 3) & 3)) << 3)];
            O0 = __builtin_amdgcn_mfma_f32_16x16x32_bf16(pf, vf0, O0, 0, 0, 0);
            O1 = __builtin_amdgcn_mfma_f32_16x16x32_bf16(pf, vf1, O1, 0, 0, 0);
            O2 = __builtin_amdgcn_mfma_f32_16x16x32_bf16(pf, vf2, O2, 0, 0, 0);
            O3 = __builtin_amdgcn_mfma_f32_16x16x32_bf16(pf, vf3, O3, 0, 0, 0);

            kvP = kvN; vvP = vvN;
        }

        #pragma unroll
        for (int r = 0; r < 4; r++) {
            float l = lst[r];
            #pragma unroll
            for (int mk = 1; mk < 16; mk <<= 1) l += __shfl_xor(l, mk);
            float inv = 1.0f / l;
            int q = 16 * w + quad * 4 + r;
            int i = 2 * (qq0 + q) + p;
            if (!gmap[i]) {   // global rows are written by the gpart blocks instead
                short* dst = ao + ((size_t)b * SS + i) * DMM + h * HDD;
                dst[col]      = f2bf(O0[r] * inv);
                dst[col + 16] = f2bf(O1[r] * inv);
                dst[col + 32] = f2bf(O2[r] * inv);
                dst[col + 48] = f2bf(O3[r] * inv);
            }
        }
    } else {
        // ---------- global rows: one block per (b,h), full 2048-key loop, no partials ----------
        short* Qs  = (short*)smem;            // 32*72
        short* Ksf = Qs + 32 * 72;            // 2 x 32*72
        short* Vtf = Ksf + 2 * 32 * 72;       // 2 x 64*40
        short* Ps  = Vtf + 2 * 64 * 40;       // 4*16*40

        int r0 = bid - 1024;
        int h = r0 & 15, b = r0 >> 4;

        const short* Qb = qh + ((size_t)(b * HH + h) * SS) * HDD;
        const short* Kb = kh + ((size_t)(b * HH + h) * SS) * HDD;
        const short* Vb = vh + ((size_t)(b * HH + h) * SS) * HDD;

        int row8 = t >> 3, dim8 = (t & 7) * 8;
        {
            int cq = row8 < nG ? row8 : 0;
            int src = glist[cq];
            short8 qv = *(const short8*)(Qb + (size_t)src * HDD + dim8);
            *(short8*)&Qs[row8 * 72 + dim8] = qv;
        }
        __syncthreads();

        int lane = t & 63, w = t >> 6;
        int quad = lane >> 4, col = lane & 15;
        int g = w >> 1, qt = w & 1;

        short8 qf0 = *(short8*)&Qs[(qt * 16 + col) * 72 + quad * 8];
        short8 qf1 = *(short8*)&Qs[(qt * 16 + col) * 72 + 32 + quad * 8];

        float4v O0 = {0,0,0,0}, O1 = {0,0,0,0}, O2 = {0,0,0,0}, O3 = {0,0,0,0};
        float lst[4] = {0.f, 0.f, 0.f, 0.f};

        for (int chunk = 0; chunk < 32; chunk++) {
            __syncthreads();
            int r64 = t >> 2, dimb = (t & 3) * 16;
            int j = chunk * 64 + r64;
            const short* kp = Kb + (size_t)j * HDD + dimb;
            const short* vp = Vb + (size_t)j * HDD + dimb;
            short8 k0 = *(const short8*)kp, k1 = *(const short8*)(kp + 8);
            short8 v0 = *(const short8*)vp, v1 = *(const short8*)(vp + 8);
            int half = r64 >> 5, r32 = r64 & 31;
            short* Ksh = Ksf + half * (32 * 72);
            short* Vth = Vtf + half * (64 * 40);
            *(short8*)&Ksh[r32 * 72 + dimb]     = k0;
            *(short8*)&Ksh[r32 * 72 + dimb + 8] = k1;
            #pragma unroll
            for (int u = 0; u < 8; u++) {
                int d = dimb + u;
                Vth[VSL(d, r32)] = v0[u];
            }
            #pragma unroll
            for (int u = 0; u < 8; u++) {
                int d = dimb + 8 + u;
                Vth[VSL(d, r32)] = v1[u];
            }
            __syncthreads();

            short* Ksg = Ksf + g * (32 * 72);
            short* Vtg = Vtf + g * (64 * 40);
            short8 kA0 = *(short8*)&Ksg[col * 72 + quad * 8];
            short8 kA1 = *(short8*)&Ksg[col * 72 + 32 + quad * 8];
            short8 kB0 = *(short8*)&Ksg[(16 + col) * 72 + quad * 8];
            short8 kB1 = *(short8*)&Ksg[(16 + col) * 72 + 32 + quad * 8];
            float4v sA = {0,0,0,0}, sB = {0,0,0,0};
            sA = __builtin_amdgcn_mfma_f32_16x16x32_bf16(qf0, kA0, sA, 0, 0, 0);
            sA = __builtin_amdgcn_mfma_f32_16x16x32_bf16(qf1, kA1, sA, 0, 0, 0);
            sB = __builtin_amdgcn_mfma_f32_16x16x32_bf16(qf0, kB0, sB, 0, 0, 0);
            sB = __builtin_amdgcn_mfma_f32_16x16x32_bf16(qf1, kB1, sB, 0, 0, 0);

            #pragma unroll
            for (int r = 0; r < 4; r++) {
                float pa = exp2f(sA[r] * SCALE2);
                float pb = exp2f(sB[r] * SCALE2);
                lst[r] += pa + pb;
                Ps[(w * 16 + quad * 4 + r) * 40 + col]      = f2bf(pa);
                Ps[(w * 16 + quad * 4 + r) * 40 + col + 16] = f2bf(pb);
            }
            asm volatile("s_waitcnt lgkmcnt(0)" ::: "memory");

            short8 pf  = *(short8*)&Ps[(w * 16 + col) * 40 + quad * 8];
            short8 vf0 = *(short8*)&Vtg[(col) * 40 + ((quad ^ ((col >> 3) & 3)) << 3)];
            short8 vf1 = *(short8*)&Vtg[(16 + col) * 40 + ((quad ^ (((16 + col) >> 3) & 3)) << 3)];
            short8 vf2 = *(short8*)&Vtg[(32 + col) * 40 + ((quad ^ (((32 + col) >> 3) & 3)) << 3)];
            short8 vf3 = *(short8*)&Vtg[(48 + col) * 40 + ((quad ^ (((48 + col) >> 3) & 3)) << 3)];
            O0 = __builtin_amdgcn_mfma_f32_16x16x32_bf16(pf, vf0, O0, 0, 0, 0);
            O1 = __builtin_amdgcn_mfma_f32_16x16x32_bf16(pf, vf1, O1, 0, 0, 0);
            O2 = __builtin_amdgcn_mfma_f32_16x16x32_bf16(pf, vf2, O2, 0, 0, 0);
            O3 = __builtin_amdgcn_mfma_f32_16x16x32_bf16(pf, vf3, O3, 0, 0, 0);
        }

        // -------- combine the two g-half waves through LDS, write ao global rows --------
        float lred[4];
        #pragma unroll
        for (int r = 0; r < 4; r++) {
            float l = lst[r];
            #pragma unroll
            for (int mk = 1; mk < 16; mk <<= 1) l += __shfl_xor(l, mk);
            lred[r] = l;
        }
        __syncthreads();                       // all waves done reading Ks/Vt/Ps
        float* comb = (float*)smem;            // [2 qt][64 lane][20] = 10240 B
        if (g == 1) {
            float* dstL = comb + ((qt << 6) + lane) * 20;
            #pragma unroll
            for (int r = 0; r < 4; r++) {
                dstL[r]      = O0[r];
                dstL[4 + r]  = O1[r];
                dstL[8 + r]  = O2[r];
                dstL[12 + r] = O3[r];
                dstL[16 + r] = lred[r];
            }
        }
        __syncthreads();
        if (g == 0) {
            float* srcL = comb + ((qt << 6) + lane) * 20;
            #pragma unroll
            for (int r = 0; r < 4; r++) {
                int q = qt * 16 + quad * 4 + r;
                if (q < nG) {
                    float L = lred[r] + srcL[16 + r];
                    float inv = 1.0f / L;
                    int i = glist[q];
                    short* dst = ao + ((size_t)b * SS + i) * DMM + h * HDD;
                    dst[col]      = f2bf((O0[r] + srcL[r])      * inv);
                    dst[col + 16] = f2bf((O1[r] + srcL[4 + r])  * inv);
                    dst[col + 32] = f2bf((O2[r] + srcL[8 + r])  * inv);
                    dst[col + 48] = f2bf((O3[r] + srcL[12 + r]) * inv);
                }
            }
        }
    }
}

extern "C" void kernel_launch(void* const* d_in, const int* in_sizes, int n_in,
                              void* d_out, int out_size, void* d_ws, size_t ws_size,
                              hipStream_t stream) {
    const float* q  = (const float*)d_in[0];
    const float* k  = (const float*)d_in[1];
    const float* v  = (const float*)d_in[2];
    const float* Wq = (const float*)d_in[3];
    const float* Wk = (const float*)d_in[4];
    const float* Wv = (const float*)d_in[5];
    const float* Wo = (const float*)d_in[6];
    const float* bq = (const float*)d_in[7];
    const float* bk = (const float*)d_in[8];
    const float* bv = (const float*)d_in[9];
    const float* bo = (const float*)d_in[10];
    const int* gidx = (const int*)d_in[11];
    float* out = (float*)d_out;

    // ws (64.03 MB): 32KB hdr | qh,kh,vh,ao bf16 8MB ea | wbf 8MB | abf 24MB
    const size_t NE = (size_t)BB * SS * DMM;   // 4M
    const size_t WE = (size_t)DMM * DMM;       // 1M
    int*   g      = (int*)d_ws;
    int*   glist  = g + SS;
    int*   gcount = glist + SS;
    short* qh     = (short*)((char*)d_ws + 32768);
    short* kh     = qh + NE;
    short* vh     = kh + NE;
    short* ao     = vh + NE;
    short* wbf    = ao + NE;
    short* wo     = wbf + 3 * WE;
    short* abf    = wbf + 4 * WE;          // dead after QKV gemm

    convert_flat<<<8193, 256, 0, stream>>>(q, k, v, Wq, Wk, Wv, Wo, abf, wbf,
                                           gidx, g, glist, gcount);

    dim3 gq(64, 3);    // batched QKV, 256x256 tiles: 192 blocks, 512 threads
    gemm256<1, 1><<<gq, 512, 0, stream>>>(abf, wbf, bq, bk, bv, qh, kh, vh);

    attn_fused<<<1056, 256, 0, stream>>>(qh, kh, vh, glist, gcount, g, ao);

    gemm128wo<<<256, 512, 0, stream>>>(ao, wo, bo, out);   // Wo: full CU coverage
}

// Round 11
// 208.497 us; speedup vs baseline: 1.2223x; 1.0857x over previous
//
#include <hip/hip_runtime.h>
#include <hip/hip_bf16.h>
#include <math.h>

#define BB 2
#define SS 2048
#define DMM 1024
#define HH 16
#define HDD 64
#define NGLOB 32
#define MM 4096   // B*S
#define SCALE2 0.18033688f   // 0.125 * log2(e): exp(s/8) == exp2(s*SCALE2)

typedef __attribute__((ext_vector_type(8))) short short8;
typedef __attribute__((ext_vector_type(4))) float float4v;

__device__ __forceinline__ short f2bf(float f) {
    union { float f; unsigned u; } x; x.f = f;
    unsigned r = (x.u + 0x7fffu + ((x.u >> 16) & 1u)) >> 16;  // RNE
    return (short)r;
}

// async 16B global->LDS (m97 path). LDS dest = wave-uniform base + lane*16.
#define ASYNC16(gp, lp) __builtin_amdgcn_global_load_lds( \
    (__attribute__((address_space(1))) void*)(gp), \
    (__attribute__((address_space(3))) void*)(lp), 16, 0, 0)

// Vt slot swizzle: key-chunk XORed with dim-derived tag -> breaks the
// dim*stride==0 (mod 32 banks) collapse on transpose stores (16-way -> 4-way).
#define VSL(dim, key) ((dim) * 40 + (((((key) >> 3) ^ (((dim) >> 3) & 3)) << 3) | ((key) & 7)))

// ---------------- flat convert fp32->bf16 + setup_globals (block 8192) ----------------
// Exact 1D grid (8193 blocks): q 0..2047, k 2048..4095, v 4096..6143, weights 6144..8191
// (512 each), setup 8192. No idle blocks (R9-verified).
__global__ __launch_bounds__(256)
void convert_flat(const float* __restrict__ q, const float* __restrict__ k,
                  const float* __restrict__ v,
                  const float* __restrict__ w0, const float* __restrict__ w1,
                  const float* __restrict__ w2, const float* __restrict__ w3,
                  short* __restrict__ abf, short* __restrict__ wbf,
                  const int* __restrict__ gidx, int* __restrict__ g,
                  int* __restrict__ glist, int* __restrict__ gcount) {
    int bid = blockIdx.x;
    int t = threadIdx.x;
    if (bid == 6144 + 2048) {          // setup_globals
        for (int i = t; i < SS; i += 256) g[i] = 0;
        if (t == 0) *gcount = 0;
        __syncthreads();
        if (t < NGLOB) {
            int j = gidx[t];
            if (j >= 0 && j < SS) g[j] = 1;
        }
        __syncthreads();
        for (int j = t; j < SS; j += 256) {
            if (g[j]) {
                int p = atomicAdd(gcount, 1);
                glist[p] = j;
            }
        }
        return;
    }
    const float* src;
    short* dst;
    if (bid < 6144) {                  // q/k/v: 4M elems each = 2048 blocks each
        int z = bid >> 11;
        size_t off = ((size_t)(bid & 2047) << 11) + (size_t)t * 8;
        src = ((z == 0) ? q : (z == 1) ? k : v) + off;
        dst = abf + ((size_t)z << 22) + off;
    } else {                           // weights: 1M elems each = 512 blocks each
        int y = (bid - 6144) >> 9;
        size_t off = ((size_t)((bid - 6144) & 511) << 11) + (size_t)t * 8;
        src = ((y == 0) ? w0 : (y == 1) ? w1 : (y == 2) ? w2 : w3) + off;
        dst = wbf + ((size_t)y << 20) + off;
    }
    float4 a = *(const float4*)(src);
    float4 b = *(const float4*)(src + 4);
    short8 s;
    s[0]=f2bf(a.x); s[1]=f2bf(a.y); s[2]=f2bf(a.z); s[3]=f2bf(a.w);
    s[4]=f2bf(b.x); s[5]=f2bf(b.y); s[6]=f2bf(b.z); s[7]=f2bf(b.w);
    *(short8*)dst = s;
}

// ---------------- 256x256/BK=64 MFMA GEMM: true 8-phase interleave (R6-verified) ----------------
// UNCHANGED from R6 (protect the win).
template<int OBF, int HEADSPLIT>
__global__ __launch_bounds__(512, 2)
void gemm256(const short* __restrict__ Abase, const short* __restrict__ Wbase,
             const float* __restrict__ b0, const float* __restrict__ b1,
             const float* __restrict__ b2,
             void* __restrict__ O0p, void* __restrict__ O1p, void* __restrict__ O2p) {
    __shared__ short As[2][256 * 64];   // 64 KB
    __shared__ short Ws[2][256 * 64];   // 64 KB

    int t = threadIdx.x;
    int z = blockIdx.y;
    const short* A    = Abase + (size_t)z * ((size_t)MM * DMM);
    const short* W    = Wbase + (size_t)z * ((size_t)DMM * DMM);
    const float* bias = (z == 0) ? b0 : (z == 1) ? b1 : b2;
    void* outp        = (z == 0) ? O0p : (z == 1) ? O1p : O2p;

    int bid = blockIdx.x;
    int mt = bid & 15, nt = bid >> 4;   // bid%8 == mt%8: nt-blocks of one mt share an XCD
    int m0 = mt * 256, n0 = nt * 256;

    int lane = t & 63, w = t >> 6;
    int quad = lane >> 4, col = lane & 15;
    int wm = (w >> 2) * 128;
    int wn = (w & 3) * 64;

    float4v acc[8][4];
    #pragma unroll
    for (int i = 0; i < 8; i++)
        #pragma unroll
        for (int j = 0; j < 4; j++) acc[i][j] = (float4v){0, 0, 0, 0};

    int srow = t >> 3;
    int scol = ((t & 7) ^ (srow & 7)) * 8;
    const short* Ap = A + (size_t)(m0 + srow) * DMM + scol;
    const short* Wp = W + (size_t)(n0 + srow) * DMM + scol;

    #define ST_W(bf, tt, h) ASYNC16(Wp + (size_t)(h) * 64 * DMM + (size_t)(tt) * 64, \
                                    &Ws[bf][(h) * 4096 + t * 8])
    #define ST_A(bf, tt, h) ASYNC16(Ap + (size_t)(h) * 64 * DMM + (size_t)(tt) * 64, \
                                    &As[bf][(h) * 4096 + t * 8])

    int c7 = col & 7;

    // prologue: stage step 0 in counted order, certify idx 0..5
    ST_W(0, 0, 0); ST_W(0, 0, 1); ST_W(0, 0, 2); ST_W(0, 0, 3);
    ST_A(0, 0, 0); ST_A(0, 0, 2); ST_A(0, 0, 1); ST_A(0, 0, 3);
    asm volatile("s_waitcnt vmcnt(2)" ::: "memory");
    __builtin_amdgcn_s_barrier();

    for (int it = 0; it < 16; it++) {
        int cur = it & 1, nb = cur ^ 1;
        bool pf = (it < 15);

        short8 bF[4][2];
        #pragma unroll
        for (int j = 0; j < 4; j++) {
            int rB = (wn + 16 * j + col) * 64;
            #pragma unroll
            for (int ks = 0; ks < 2; ks++)
                bF[j][ks] = *(short8*)&Ws[cur][rB + ((((ks << 2) | quad) ^ c7) << 3)];
        }

        #pragma unroll
        for (int p = 0; p < 4; p++) {
            short8 aF[2][2];
            #pragma unroll
            for (int u = 0; u < 2; u++) {
                int rA = (wm + 16 * (2 * p + u) + col) * 64;
                #pragma unroll
                for (int ks = 0; ks < 2; ks++)
                    aF[u][ks] = *(short8*)&As[cur][rA + ((((ks << 2) | quad) ^ c7) << 3)];
            }
            if (pf) {
                if (p == 0)      { ST_W(nb, it + 1, 0); ST_W(nb, it + 1, 1); }
                else if (p == 1) { ST_W(nb, it + 1, 2); ST_W(nb, it + 1, 3); }
                else if (p == 2) { ST_A(nb, it + 1, 0); ST_A(nb, it + 1, 2); }
                else             { ST_A(nb, it + 1, 1); ST_A(nb, it + 1, 3); }
            }
            __builtin_amdgcn_s_barrier();
            __builtin_amdgcn_s_setprio(1);
            #pragma unroll
            for (int ks = 0; ks < 2; ks++)
                #pragma unroll
                for (int u = 0; u < 2; u++)
                    #pragma unroll
                    for (int j = 0; j < 4; j++)
                        acc[2 * p + u][j] = __builtin_amdgcn_mfma_f32_16x16x32_bf16(
                            aF[u][ks], bF[j][ks], acc[2 * p + u][j], 0, 0, 0);
            __builtin_amdgcn_s_setprio(0);
            if (p == 1) {
                if (pf) asm volatile("s_waitcnt vmcnt(4)" ::: "memory");
                else    asm volatile("s_waitcnt vmcnt(0)" ::: "memory");
            }
            if (p == 3 && pf)
                asm volatile("s_waitcnt vmcnt(2)" ::: "memory");
            __builtin_amdgcn_s_barrier();
        }
    }
    #undef ST_W
    #undef ST_A

    #pragma unroll
    for (int i = 0; i < 8; i++) {
        #pragma unroll
        for (int j = 0; j < 4; j++) {
            int n = n0 + wn + 16 * j + col;
            float bn = bias[n];
            #pragma unroll
            for (int r = 0; r < 4; r++) {
                int m = m0 + wm + 16 * i + quad * 4 + r;
                float val = acc[i][j][r] + bn;
                size_t idx;
                if (HEADSPLIT) {
                    int b = m >> 11;
                    int s = m & 2047;
                    int h = n >> 6;
                    int hd = n & 63;
                    idx = (((size_t)b * HH + h) * SS + s) * HDD + hd;
                } else {
                    idx = (size_t)m * DMM + n;
                }
                if (OBF) ((short*)outp)[idx] = f2bf(val);
                else     ((float*)outp)[idx] = val;
            }
        }
    }
}

// ---------------- Wo GEMM: 128x128/BK=64, 512 thr, T2 swizzle + counted vmcnt + T5 --------------
// UNCHANGED from R5/R6. 256 blocks = full CU coverage.
__global__ __launch_bounds__(512, 2)
void gemm128wo(const short* __restrict__ A, const short* __restrict__ W,
               const float* __restrict__ bias, float* __restrict__ out) {
    __shared__ short As[2][128 * 64];   // 32 KB
    __shared__ short Ws[2][128 * 64];   // 32 KB

    int t = threadIdx.x;
    int bid = blockIdx.x;
    int mt = bid & 31, nt = bid >> 5;
    int m0 = mt * 128, n0 = nt * 128;

    int lane = t & 63, w = t >> 6;
    int quad = lane >> 4, col = lane & 15;
    int wm = (w >> 2) * 64;
    int wn = (w & 3) * 32;

    float4v acc[4][2];
    #pragma unroll
    for (int i = 0; i < 4; i++)
        #pragma unroll
        for (int j = 0; j < 2; j++) acc[i][j] = (float4v){0, 0, 0, 0};

    int srow = t >> 3;
    int scol = ((t & 7) ^ (srow & 7)) * 8;
    const short* Ap = A + (size_t)(m0 + srow) * DMM + scol;
    const short* Wp = W + (size_t)(n0 + srow) * DMM + scol;

    #define STAGEWO(bf, tt) do { size_t kk = (size_t)(tt) * 64; \
        ASYNC16(Ap + kk,                      &As[bf][t * 8]); \
        ASYNC16(Ap + 64 * (size_t)DMM + kk,   &As[bf][4096 + t * 8]); \
        ASYNC16(Wp + kk,                      &Ws[bf][t * 8]); \
        ASYNC16(Wp + 64 * (size_t)DMM + kk,   &Ws[bf][4096 + t * 8]); \
    } while (0)

    int c7 = col & 7;

    STAGEWO(0, 0);

    for (int it = 0; it < 16; it++) {
        int cur = it & 1;
        if (it < 15) {
            STAGEWO(cur ^ 1, it + 1);
            asm volatile("s_waitcnt vmcnt(4)" ::: "memory");
        } else {
            asm volatile("s_waitcnt vmcnt(0)" ::: "memory");
        }
        __builtin_amdgcn_s_barrier();

        short8 bF[2][2];
        #pragma unroll
        for (int j = 0; j < 2; j++) {
            int rB = (wn + 16 * j + col) * 64;
            #pragma unroll
            for (int ks = 0; ks < 2; ks++)
                bF[j][ks] = *(short8*)&Ws[cur][rB + ((((ks << 2) | quad) ^ c7) << 3)];
        }

        #pragma unroll
        for (int p = 0; p < 2; p++) {
            if (p) __builtin_amdgcn_s_barrier();
            short8 aF[2][2];
            #pragma unroll
            for (int u = 0; u < 2; u++) {
                int rA = (wm + 16 * (2 * p + u) + col) * 64;
                #pragma unroll
                for (int ks = 0; ks < 2; ks++)
                    aF[u][ks] = *(short8*)&As[cur][rA + ((((ks << 2) | quad) ^ c7) << 3)];
            }
            __builtin_amdgcn_s_setprio(1);
            #pragma unroll
            for (int ks = 0; ks < 2; ks++)
                #pragma unroll
                for (int u = 0; u < 2; u++)
                    #pragma unroll
                    for (int j = 0; j < 2; j++)
                        acc[2 * p + u][j] = __builtin_amdgcn_mfma_f32_16x16x32_bf16(
                            aF[u][ks], bF[j][ks], acc[2 * p + u][j], 0, 0, 0);
            __builtin_amdgcn_s_setprio(0);
        }
        __builtin_amdgcn_s_barrier();
    }
    #undef STAGEWO

    #pragma unroll
    for (int i = 0; i < 4; i++) {
        #pragma unroll
        for (int j = 0; j < 2; j++) {
            int n = n0 + wn + 16 * j + col;
            float bn = bias[n];
            #pragma unroll
            for (int r = 0; r < 4; r++) {
                int m = m0 + wm + 16 * i + quad * 4 + r;
                out[(size_t)m * DMM + n] = acc[i][j][r] + bn;
            }
        }
    }
}

// ---------------- fused attention: band (0..1023) + global_part (1024..1279) -------------------
// EXACT R6 structure (verified <40.3us): band writes ALL rows; 256 gpart blocks (8 per
// (b,h), 4 chunks each) write pl/pO partials. NO fences, NO atomics - the separate
// stream-ordered global_merge kernel provides inter-kernel ordering + cache flush.
__global__ __launch_bounds__(256)
void attn_fused(const short* __restrict__ qh, const short* __restrict__ kh,
                const short* __restrict__ vh, const int* __restrict__ glist,
                const int* __restrict__ gcount, short* __restrict__ ao,
                float* __restrict__ pl, float* __restrict__ pO) {
    __shared__ __align__(16) char smem[29184];
    int t = threadIdx.x;
    int bid = blockIdx.x;
    int nG = *gcount;

    if (bid < 1024) {
        // ---------- banded attention (XCD-local, swizzled Vt, interval mask, T14 prefetch) -------
        short* Qs = (short*)smem;            // 64*72
        short* Ks = Qs + 64 * 72;            // 32*72
        short* Vt = Ks + 32 * 72;            // 64*40
        short* Ps = Vt + 64 * 40;            // 4*16*40
        int*   gjs = (int*)(Ps + 4 * 16 * 40);  // 32 ints

        int xcd = bid & 7, idx = bid >> 3;
        int gl  = idx >> 4;
        int qt  = idx & 15;
        int gid = xcd * 8 + gl;
        int z   = gid >> 4;
        int h   = gid & 15;
        int b = z >> 1, p = z & 1;
        int qq0 = qt * 64;

        const short* Qb = qh + ((size_t)(b * HH + h) * SS) * HDD;
        const short* Kb = kh + ((size_t)(b * HH + h) * SS) * HDD;
        const short* Vb = vh + ((size_t)(b * HH + h) * SS) * HDD;

        int row8 = t >> 3;
        int dim8 = (t & 7) * 8;

        #pragma unroll
        for (int rr = 0; rr < 2; rr++) {
            int row = rr * 32 + row8;
            int i = 2 * (qq0 + row) + p;
            short8 qv = *(const short8*)(Qb + (size_t)i * HDD + dim8);
            *(short8*)&Qs[row * 72 + dim8] = qv;
        }
        if (t < 32) gjs[t] = (t < nG) ? glist[t] : -1000000;
        __syncthreads();

        int lane = t & 63, w = t >> 6;
        int quad = lane >> 4, col = lane & 15;

        short8 qf0 = *(short8*)&Qs[(16 * w + col) * 72 + quad * 8];
        short8 qf1 = *(short8*)&Qs[(16 * w + col) * 72 + 32 + quad * 8];

        float4v O0 = {0,0,0,0}, O1 = {0,0,0,0}, O2 = {0,0,0,0}, O3 = {0,0,0,0};
        float lst[4] = {0.f, 0.f, 0.f, 0.f};

        short8 kvP, vvP, kvN, vvN;
        {
            int srow = 2 * (qq0 - 256 + row8) + p;
            srow = srow < 0 ? 0 : (srow > SS - 1 ? SS - 1 : srow);
            kvP = *(const short8*)(Kb + (size_t)srow * HDD + dim8);
            vvP = *(const short8*)(Vb + (size_t)srow * HDD + dim8);
        }

        for (int c = 0; c < 19; c++) {
            __syncthreads();
            *(short8*)&Ks[row8 * 72 + dim8] = kvP;
            #pragma unroll
            for (int j = 0; j < 8; j++) {
                int d = dim8 + j;
                Vt[VSL(d, row8)] = vvP[j];
            }
            if (c < 18) {
                int cn = c + 1;
                int ch0n = qq0 - 256 + cn * 32;
                int srow;
                if (cn < 18) srow = 2 * (ch0n + row8) + p;
                else         srow = (row8 < nG) ? gjs[row8] : 0;
                srow = srow < 0 ? 0 : (srow > SS - 1 ? SS - 1 : srow);
                kvN = *(const short8*)(Kb + (size_t)srow * HDD + dim8);
                vvN = *(const short8*)(Vb + (size_t)srow * HDD + dim8);
            }
            __syncthreads();

            int ch0 = qq0 - 256 + c * 32;

            short8 kA0 = *(short8*)&Ks[col * 72 + quad * 8];
            short8 kA1 = *(short8*)&Ks[col * 72 + 32 + quad * 8];
            short8 kB0 = *(short8*)&Ks[(16 + col) * 72 + quad * 8];
            short8 kB1 = *(short8*)&Ks[(16 + col) * 72 + 32 + quad * 8];
            float4v sA = {0,0,0,0}, sB = {0,0,0,0};
            sA = __builtin_amdgcn_mfma_f32_16x16x32_bf16(qf0, kA0, sA, 0, 0, 0);
            sA = __builtin_amdgcn_mfma_f32_16x16x32_bf16(qf1, kA1, sA, 0, 0, 0);
            sB = __builtin_amdgcn_mfma_f32_16x16x32_bf16(qf0, kB0, sB, 0, 0, 0);
            sB = __builtin_amdgcn_mfma_f32_16x16x32_bf16(qf1, kB1, sB, 0, 0, 0);

            if (c < 18) {
                int nlo = -ch0;
                int nhi = 1023 - ch0;
                #pragma unroll
                for (int r = 0; r < 4; r++) {
                    int qq = qq0 + 16 * w + quad * 4 + r;
                    int u  = qq - ch0;
                    int lo = max(u - 256, nlo);
                    int hi = min(u + 256, nhi);
                    bool vA = (col >= lo) && (col <= hi);
                    bool vB = (col + 16 >= lo) && (col + 16 <= hi);
                    float pa = vA ? exp2f(sA[r] * SCALE2) : 0.f;
                    float pb = vB ? exp2f(sB[r] * SCALE2) : 0.f;
                    lst[r] += pa + pb;
                    Ps[(w * 16 + quad * 4 + r) * 40 + col]      = f2bf(pa);
                    Ps[(w * 16 + quad * 4 + r) * 40 + col + 16] = f2bf(pb);
                }
            } else {
                #pragma unroll
                for (int r = 0; r < 4; r++) {
                    int qq = qq0 + 16 * w + quad * 4 + r;
                    int i = 2 * qq + p;
                    int jA = gjs[col], jB = gjs[col + 16];
                    int dA = jA - i, dB = jB - i;
                    int aA = dA < 0 ? -dA : dA;
                    int aB = dB < 0 ? -dB : dB;
                    bool vA = (jA >= 0) && !((aA <= 512) && ((dA & 1) == 0));
                    bool vB = (jB >= 0) && !((aB <= 512) && ((dB & 1) == 0));
                    float pa = vA ? exp2f(sA[r] * SCALE2) : 0.f;
                    float pb = vB ? exp2f(sB[r] * SCALE2) : 0.f;
                    lst[r] += pa + pb;
                    Ps[(w * 16 + quad * 4 + r) * 40 + col]      = f2bf(pa);
                    Ps[(w * 16 + quad * 4 + r) * 40 + col + 16] = f2bf(pb);
                }
            }
            asm volatile("s_waitcnt lgkmcnt(0)" ::: "memory");

            short8 pf  = *(short8*)&Ps[(w * 16 + col) * 40 + quad * 8];
            short8 vf0 = *(short8*)&Vt[(col) * 40 + ((quad ^ ((col >> 3) & 3)) << 3)];
            short8 vf1 = *(short8*)&Vt[(16 + col) * 40 + ((quad ^ (((16 + col) >> 3) & 3)) << 3)];
            short8 vf2 = *(short8*)&Vt[(32 + col) * 40 + ((quad ^ (((32 + col) >> 3) & 3)) << 3)];
            short8 vf3 = *(short8*)&Vt[(48 + col) * 40 + ((quad ^ (((48 + col) >> 3) & 3)) << 3)];
            O0 = __builtin_amdgcn_mfma_f32_16x16x32_bf16(pf, vf0, O0, 0, 0, 0);
            O1 = __builtin_amdgcn_mfma_f32_16x16x32_bf16(pf, vf1, O1, 0, 0, 0);
            O2 = __builtin_amdgcn_mfma_f32_16x16x32_bf16(pf, vf2, O2, 0, 0, 0);
            O3 = __builtin_amdgcn_mfma_f32_16x16x32_bf16(pf, vf3, O3, 0, 0, 0);

            kvP = kvN; vvP = vvN;
        }

        #pragma unroll
        for (int r = 0; r < 4; r++) {
            float l = lst[r];
            #pragma unroll
            for (int mk = 1; mk < 16; mk <<= 1) l += __shfl_xor(l, mk);
            float inv = 1.0f / l;
            int q = 16 * w + quad * 4 + r;
            int i = 2 * (qq0 + q) + p;
            short* dst = ao + ((size_t)b * SS + i) * DMM + h * HDD;
            dst[col]      = f2bf(O0[r] * inv);
            dst[col + 16] = f2bf(O1[r] * inv);
            dst[col + 32] = f2bf(O2[r] * inv);
            dst[col + 48] = f2bf(O3[r] * inv);
        }
    } else {
        // ---------- global rows: split-K MFMA partials (no-max softmax) ----------
        short* Qs  = (short*)smem;            // 32*72
        short* Ksf = Qs + 32 * 72;            // 2 x 32*72
        short* Vtf = Ksf + 2 * 32 * 72;       // 2 x 64*40
        short* Ps  = Vtf + 2 * 64 * 40;       // 4*16*40

        int r0 = bid - 1024;
        int s = r0 & 7, h = (r0 >> 3) & 15, b = r0 >> 7;

        const short* Qb = qh + ((size_t)(b * HH + h) * SS) * HDD;
        const short* Kb = kh + ((size_t)(b * HH + h) * SS) * HDD;
        const short* Vb = vh + ((size_t)(b * HH + h) * SS) * HDD;

        int row8 = t >> 3, dim8 = (t & 7) * 8;
        {
            int cq = row8 < nG ? row8 : 0;
            int src = glist[cq];
            short8 qv = *(const short8*)(Qb + (size_t)src * HDD + dim8);
            *(short8*)&Qs[row8 * 72 + dim8] = qv;
        }
        __syncthreads();

        int lane = t & 63, w = t >> 6;
        int quad = lane >> 4, col = lane & 15;
        int g = w >> 1, qt = w & 1;

        short8 qf0 = *(short8*)&Qs[(qt * 16 + col) * 72 + quad * 8];
        short8 qf1 = *(short8*)&Qs[(qt * 16 + col) * 72 + 32 + quad * 8];

        float4v O0 = {0,0,0,0}, O1 = {0,0,0,0}, O2 = {0,0,0,0}, O3 = {0,0,0,0};
        float lst[4] = {0.f, 0.f, 0.f, 0.f};

        int js0 = s * 256;
        for (int it = 0; it < 4; it++) {
            __syncthreads();
            int r64 = t >> 2, dimb = (t & 3) * 16;
            int j = js0 + it * 64 + r64;
            const short* kp = Kb + (size_t)j * HDD + dimb;
            const short* vp = Vb + (size_t)j * HDD + dimb;
            short8 k0 = *(const short8*)kp, k1 = *(const short8*)(kp + 8);
            short8 v0 = *(const short8*)vp, v1 = *(const short8*)(vp + 8);
            int half = r64 >> 5, r32 = r64 & 31;
            short* Ksh = Ksf + half * (32 * 72);
            short* Vth = Vtf + half * (64 * 40);
            *(short8*)&Ksh[r32 * 72 + dimb]     = k0;
            *(short8*)&Ksh[r32 * 72 + dimb + 8] = k1;
            #pragma unroll
            for (int u = 0; u < 8; u++) {
                int d = dimb + u;
                Vth[VSL(d, r32)] = v0[u];
            }
            #pragma unroll
            for (int u = 0; u < 8; u++) {
                int d = dimb + 8 + u;
                Vth[VSL(d, r32)] = v1[u];
            }
            __syncthreads();

            short* Ksg = Ksf + g * (32 * 72);
            short* Vtg = Vtf + g * (64 * 40);
            short8 kA0 = *(short8*)&Ksg[col * 72 + quad * 8];
            short8 kA1 = *(short8*)&Ksg[col * 72 + 32 + quad * 8];
            short8 kB0 = *(short8*)&Ksg[(16 + col) * 72 + quad * 8];
            short8 kB1 = *(short8*)&Ksg[(16 + col) * 72 + 32 + quad * 8];
            float4v sA = {0,0,0,0}, sB = {0,0,0,0};
            sA = __builtin_amdgcn_mfma_f32_16x16x32_bf16(qf0, kA0, sA, 0, 0, 0);
            sA = __builtin_amdgcn_mfma_f32_16x16x32_bf16(qf1, kA1, sA, 0, 0, 0);
            sB = __builtin_amdgcn_mfma_f32_16x16x32_bf16(qf0, kB0, sB, 0, 0, 0);
            sB = __builtin_amdgcn_mfma_f32_16x16x32_bf16(qf1, kB1, sB, 0, 0, 0);

            #pragma unroll
            for (int r = 0; r < 4; r++) {
                float pa = exp2f(sA[r] * SCALE2);
                float pb = exp2f(sB[r] * SCALE2);
                lst[r] += pa + pb;
                Ps[(w * 16 + quad * 4 + r) * 40 + col]      = f2bf(pa);
                Ps[(w * 16 + quad * 4 + r) * 40 + col + 16] = f2bf(pb);
            }
            asm volatile("s_waitcnt lgkmcnt(0)" ::: "memory");

            short8 pf  = *(short8*)&Ps[(w * 16 + col) * 40 + quad * 8];
            short8 vf0 = *(short8*)&Vtg[(col) * 40 + ((quad ^ ((col >> 3) & 3)) << 3)];
            short8 vf1 = *(short8*)&Vtg[(16 + col) * 40 + ((quad ^ (((16 + col) >> 3) & 3)) << 3)];
            short8 vf2 = *(short8*)&Vtg[(32 + col) * 40 + ((quad ^ (((32 + col) >> 3) & 3)) << 3)];
            short8 vf3 = *(short8*)&Vtg[(48 + col) * 40 + ((quad ^ (((48 + col) >> 3) & 3)) << 3)];
            O0 = __builtin_amdgcn_mfma_f32_16x16x32_bf16(pf, vf0, O0, 0, 0, 0);
            O1 = __builtin_amdgcn_mfma_f32_16x16x32_bf16(pf, vf1, O1, 0, 0, 0);
            O2 = __builtin_amdgcn_mfma_f32_16x16x32_bf16(pf, vf2, O2, 0, 0, 0);
            O3 = __builtin_amdgcn_mfma_f32_16x16x32_bf16(pf, vf3, O3, 0, 0, 0);
        }

        int sp = s * 2 + g;
        size_t base = ((size_t)(b * HH + h) * 16 + sp) * 32;
        #pragma unroll
        for (int r = 0; r < 4; r++) {
            float l = lst[r];
            #pragma unroll
            for (int mk = 1; mk < 16; mk <<= 1) l += __shfl_xor(l, mk);
            int q = qt * 16 + quad * 4 + r;
            if (col == 0) pl[base + q] = l;
            float* Od = pO + (base + q) * 64;
            Od[col]      = O0[r];
            Od[col + 16] = O1[r];
            Od[col + 32] = O2[r];
            Od[col + 48] = O3[r];
        }
    }
}

// ---------------- merge 16 partials per (b,h): plain sums (stream-ordered, no fences) -----------
__global__ __launch_bounds__(256)
void global_merge(const float* __restrict__ pl, const float* __restrict__ pO,
                  const int* __restrict__ glist, const int* __restrict__ gcount,
                  short* __restrict__ ao) {
    int h = blockIdx.x, b = blockIdx.y;
    int t = threadIdx.x;
    int d = t & 63, qg = t >> 6;
    int nG = *gcount;
    size_t bh = ((size_t)(b * HH + h) * 16) * 32;

    for (int q = qg; q < nG; q += 4) {
        float L = 0.f, acc = 0.f;
        #pragma unroll
        for (int sp = 0; sp < 16; sp++) {
            L   += pl[bh + sp * 32 + q];
            acc += pO[(bh + sp * 32 + q) * 64 + d];
        }
        int i = glist[q];
        ao[((size_t)b * SS + i) * DMM + h * HDD + d] = f2bf(acc / L);
    }
}

extern "C" void kernel_launch(void* const* d_in, const int* in_sizes, int n_in,
                              void* d_out, int out_size, void* d_ws, size_t ws_size,
                              hipStream_t stream) {
    const float* q  = (const float*)d_in[0];
    const float* k  = (const float*)d_in[1];
    const float* v  = (const float*)d_in[2];
    const float* Wq = (const float*)d_in[3];
    const float* Wk = (const float*)d_in[4];
    const float* Wv = (const float*)d_in[5];
    const float* Wo = (const float*)d_in[6];
    const float* bq = (const float*)d_in[7];
    const float* bk = (const float*)d_in[8];
    const float* bv = (const float*)d_in[9];
    const float* bo = (const float*)d_in[10];
    const int* gidx = (const int*)d_in[11];
    float* out = (float*)d_out;

    // ws (64.03 MB): 32KB hdr | qh,kh,vh,ao bf16 8MB ea | wbf 8MB | abf 24MB (aliased by pl+pO)
    const size_t NE = (size_t)BB * SS * DMM;   // 4M
    const size_t WE = (size_t)DMM * DMM;       // 1M
    int*   g      = (int*)d_ws;
    int*   glist  = g + SS;
    int*   gcount = glist + SS;
    short* qh     = (short*)((char*)d_ws + 32768);
    short* kh     = qh + NE;
    short* vh     = kh + NE;
    short* ao     = vh + NE;
    short* wbf    = ao + NE;
    short* wo     = wbf + 3 * WE;
    short* abf    = wbf + 4 * WE;          // dead after QKV gemm
    float* pl     = (float*)abf;           // alias: written by attn_fused gpart branch (later)
    float* pO     = pl + 16384;

    convert_flat<<<8193, 256, 0, stream>>>(q, k, v, Wq, Wk, Wv, Wo, abf, wbf,
                                           gidx, g, glist, gcount);

    dim3 gq(64, 3);    // batched QKV, 256x256 tiles: 192 blocks, 512 threads
    gemm256<1, 1><<<gq, 512, 0, stream>>>(abf, wbf, bq, bk, bv, qh, kh, vh);

    attn_fused<<<1280, 256, 0, stream>>>(qh, kh, vh, glist, gcount, ao, pl, pO);

    dim3 gm(HH, BB);
    global_merge<<<gm, 256, 0, stream>>>(pl, pO, glist, gcount, ao);

    gemm128wo<<<256, 512, 0, stream>>>(ao, wo, bo, out);   // Wo: full CU coverage
}